// Round 1
// baseline (4573.261 us; speedup 1.0000x reference)
//
#include <hip/hip_runtime.h>
#include <math.h>

// Problem constants
#define NN 50000
#define PP 200000
#define LL 6
#define DD 128      // IN_DIM == OUT_DIM
#define G3 384      // 3*OUT_DIM
#define HH 4        // heads

// Tiling
#define TM 32       // paths per workgroup
#define NT 256      // threads per workgroup
#define KP 16       // k-panel size
#define XSS 34      // padded LDS stride for [d][pi] tiles (pi fastest)

// ---------------------------------------------------------------------------
// Prep: transpose weights to [k][g] layout so LDS panel loads are coalesced.
// ---------------------------------------------------------------------------
__global__ void prep_kernel(const float* __restrict__ w_ih,
                            const float* __restrict__ w_hh,
                            float* __restrict__ wt_ih,
                            float* __restrict__ wt_hh) {
    int i = blockIdx.x * 256 + threadIdx.x;   // over 384*128
    if (i < G3 * DD) {
        int g = i / DD;
        int k = i - g * DD;
        wt_ih[k * G3 + g] = w_ih[i];
        wt_hh[k * G3 + g] = w_hh[i];
    }
}

// ---------------------------------------------------------------------------
// Fused GRU + attention kernel.
// Thread mapping (identical for every gate chunk so r,z live in registers):
//   tr = tid & 15  -> path pair {2tr, 2tr+1}
//   tc = tid >> 4  -> 8 gates [8tc, 8tc+8) within the 128-wide chunk
// Chunks: c=1 (z), c=0 (r), c=2 (n: i_n and h_n kept separate).
// ---------------------------------------------------------------------------
__global__ __launch_bounds__(NT, 2)
void gru_att_kernel(const float* __restrict__ x,
                    const int*   __restrict__ path_list,
                    const float* __restrict__ wt_ih,   // [128][384]
                    const float* __restrict__ wt_hh,   // [128][384]
                    const float* __restrict__ b_ih,
                    const float* __restrict__ b_hh,
                    const float* __restrict__ a,       // [128][4]
                    float* __restrict__ att_sum,       // [N][4]
                    float* __restrict__ out)           // [N][512]
{
    __shared__ float xs[DD][XSS];     // x_t tile, [k][pi]
    __shared__ float hs[DD][XSS];     // hidden state, [d][pi]
    __shared__ float wp[KP][DD];      // w_ih panel (chunk columns)
    __shared__ float vp[KP][DD];      // w_hh panel
    __shared__ int   rows_s[TM];
    __shared__ float attun_s[TM][HH];
    __shared__ float red_s[TM][8][HH];

    const int tid = threadIdx.x;
    const int tr  = tid & 15;
    const int tc  = tid >> 4;
    const int p0  = blockIdx.x * TM;
    const int pi0 = tr * 2;
    const int pi1 = pi0 + 1;

    // h0 = 0
    for (int i = tid; i < DD * TM; i += NT) {
        int k  = i >> 5;
        int pi = i & 31;
        hs[k][pi] = 0.f;
    }

    float r_reg[16], z_reg[16];

    for (int t = 0; t < LL; ++t) {
        // ---- gather x_t tile (transposed into xs[k][pi]) ----
        {
            int pi = tid >> 3;       // 0..31
            int tt = tid & 7;        // 0..7
            int node = path_list[(p0 + pi) * LL + t];
            if (t == LL - 1 && tt == 0) rows_s[pi] = node;
            const float* xrow = x + (size_t)node * DD;
            #pragma unroll
            for (int j = 0; j < 4; ++j) {
                int k0 = tt * 16 + j * 4;
                float4 v = *(const float4*)(xrow + k0);
                xs[k0 + 0][pi] = v.x;
                xs[k0 + 1][pi] = v.y;
                xs[k0 + 2][pi] = v.z;
                xs[k0 + 3][pi] = v.w;
            }
        }
        // NOTE: visibility of gather + h-init/h-update is guaranteed by the
        // first panel barrier inside each chunk below.

        // ---- chunk z (c=1), then r (c=0): combined acc = x@w + h@v + biases
        #pragma unroll
        for (int cc = 0; cc < 2; ++cc) {
            const int c = 1 - cc;    // z first, then r
            float acc[16];
            #pragma unroll
            for (int j = 0; j < 8; ++j) {
                int g = c * DD + tc * 8 + j;
                float b = b_ih[g] + b_hh[g];
                acc[j] = b; acc[8 + j] = b;
            }
            for (int p8 = 0; p8 < DD / KP; ++p8) {
                __syncthreads();
                for (int i = tid; i < KP * DD / 4; i += NT) {   // 512 float4s
                    int kk = i >> 5;
                    int gg = (i & 31) * 4;
                    int k  = p8 * KP + kk;
                    *(float4*)&wp[kk][gg] = *(const float4*)&wt_ih[k * G3 + c * DD + gg];
                    *(float4*)&vp[kk][gg] = *(const float4*)&wt_hh[k * G3 + c * DD + gg];
                }
                __syncthreads();
                #pragma unroll
                for (int kk = 0; kk < KP; ++kk) {
                    int k = p8 * KP + kk;
                    float2 xv = *(const float2*)&xs[k][pi0];
                    float2 hv = *(const float2*)&hs[k][pi0];
                    float4 w0 = *(const float4*)&wp[kk][tc * 8];
                    float4 w1 = *(const float4*)&wp[kk][tc * 8 + 4];
                    float4 v0 = *(const float4*)&vp[kk][tc * 8];
                    float4 v1 = *(const float4*)&vp[kk][tc * 8 + 4];
                    float wj[8] = {w0.x, w0.y, w0.z, w0.w, w1.x, w1.y, w1.z, w1.w};
                    float vj[8] = {v0.x, v0.y, v0.z, v0.w, v1.x, v1.y, v1.z, v1.w};
                    #pragma unroll
                    for (int j = 0; j < 8; ++j) {
                        acc[j]     += xv.x * wj[j];
                        acc[j]     += hv.x * vj[j];
                        acc[8 + j] += xv.y * wj[j];
                        acc[8 + j] += hv.y * vj[j];
                    }
                }
            }
            #pragma unroll
            for (int j = 0; j < 16; ++j) {
                float s = 1.f / (1.f + __expf(-acc[j]));
                if (c == 1) z_reg[j] = s; else r_reg[j] = s;
            }
        }

        // ---- chunk n (c=2): keep i_n and h_n separate ----
        {
            float ai[16], ah[16];
            #pragma unroll
            for (int j = 0; j < 8; ++j) {
                int g = 2 * DD + tc * 8 + j;
                ai[j] = b_ih[g]; ai[8 + j] = b_ih[g];
                ah[j] = b_hh[g]; ah[8 + j] = b_hh[g];
            }
            for (int p8 = 0; p8 < DD / KP; ++p8) {
                __syncthreads();
                for (int i = tid; i < KP * DD / 4; i += NT) {
                    int kk = i >> 5;
                    int gg = (i & 31) * 4;
                    int k  = p8 * KP + kk;
                    *(float4*)&wp[kk][gg] = *(const float4*)&wt_ih[k * G3 + 2 * DD + gg];
                    *(float4*)&vp[kk][gg] = *(const float4*)&wt_hh[k * G3 + 2 * DD + gg];
                }
                __syncthreads();
                #pragma unroll
                for (int kk = 0; kk < KP; ++kk) {
                    int k = p8 * KP + kk;
                    float2 xv = *(const float2*)&xs[k][pi0];
                    float2 hv = *(const float2*)&hs[k][pi0];
                    float4 w0 = *(const float4*)&wp[kk][tc * 8];
                    float4 w1 = *(const float4*)&wp[kk][tc * 8 + 4];
                    float4 v0 = *(const float4*)&vp[kk][tc * 8];
                    float4 v1 = *(const float4*)&vp[kk][tc * 8 + 4];
                    float wj[8] = {w0.x, w0.y, w0.z, w0.w, w1.x, w1.y, w1.z, w1.w};
                    float vj[8] = {v0.x, v0.y, v0.z, v0.w, v1.x, v1.y, v1.z, v1.w};
                    #pragma unroll
                    for (int j = 0; j < 8; ++j) {
                        ai[j]     += xv.x * wj[j];
                        ah[j]     += hv.x * vj[j];
                        ai[8 + j] += xv.y * wj[j];
                        ah[8 + j] += hv.y * vj[j];
                    }
                }
            }
            __syncthreads();   // all xs/hs reads of this step are done
            // h update: this thread exclusively owns (pi0/pi1, d=8tc..8tc+7)
            #pragma unroll
            for (int pp = 0; pp < 2; ++pp) {
                int pi = pi0 + pp;
                #pragma unroll
                for (int j = 0; j < 8; ++j) {
                    int idx = pp * 8 + j;
                    int d   = tc * 8 + j;
                    float ncand = tanhf(ai[idx] + r_reg[idx] * ah[idx]);
                    float hold  = hs[d][pi];
                    float z     = z_reg[idx];
                    hs[d][pi]   = (1.f - z) * ncand + z * hold;
                }
            }
        }
        // next iteration's first panel barrier protects the updated hs / new xs
    }

    __syncthreads();   // final h visible to all

    // ---- attention logits: att_un[pi][h] = exp(lrelu(h_pi . a[:,h])) ----
    {
        int pi = tid >> 3;
        int tt = tid & 7;
        float s0 = 0.f, s1 = 0.f, s2 = 0.f, s3 = 0.f;
        for (int d = tt * 16; d < tt * 16 + 16; ++d) {
            float hv = hs[d][pi];
            float4 av = *(const float4*)&a[d * 4];
            s0 += hv * av.x; s1 += hv * av.y; s2 += hv * av.z; s3 += hv * av.w;
        }
        red_s[pi][tt][0] = s0; red_s[pi][tt][1] = s1;
        red_s[pi][tt][2] = s2; red_s[pi][tt][3] = s3;
    }
    __syncthreads();
    if (tid < TM) {
        int pi = tid;
        int row = rows_s[pi];
        #pragma unroll
        for (int h = 0; h < HH; ++h) {
            float s = 0.f;
            #pragma unroll
            for (int tt = 0; tt < 8; ++tt) s += red_s[pi][tt][h];
            float lv = (s > 0.f) ? s : 0.2f * s;   // leaky_relu slope 0.2
            float e  = expf(lv);
            attun_s[pi][h] = e;
            atomicAdd(&att_sum[row * HH + h], e);
        }
    }
    __syncthreads();

    // ---- accumulate unnormalized numerator into out[row][h*128+d] ----
    for (int e = tid; e < TM * 512; e += NT) {
        int pi = e >> 9;
        int c  = e & 511;
        int h  = c >> 7;
        int d  = c & 127;
        float v = attun_s[pi][h] * hs[d][pi];
        atomicAdd(&out[(size_t)rows_s[pi] * 512 + c], v);
    }
}

// ---------------------------------------------------------------------------
// Normalize: out[n][h*128+d] /= att_sum[n][h]  (guard empty nodes: 0/0 -> 0)
// ---------------------------------------------------------------------------
__global__ void normalize_kernel(float* __restrict__ out,
                                 const float* __restrict__ att_sum) {
    int i = blockIdx.x * 256 + threadIdx.x;   // over N*512 = 25.6M
    if (i < NN * 512) {
        int n = i >> 9;
        int h = (i >> 7) & 3;
        float s = att_sum[n * HH + h];
        float v = out[i];
        out[i] = (s > 0.f) ? v / s : 0.f;
    }
}

extern "C" void kernel_launch(void* const* d_in, const int* in_sizes, int n_in,
                              void* d_out, int out_size, void* d_ws, size_t ws_size,
                              hipStream_t stream) {
    const float* x         = (const float*)d_in[0];
    const int*   path_list = (const int*)  d_in[1];
    const float* w_ih      = (const float*)d_in[2];
    const float* w_hh      = (const float*)d_in[3];
    const float* b_ih      = (const float*)d_in[4];
    const float* b_hh      = (const float*)d_in[5];
    const float* a         = (const float*)d_in[6];
    float* out = (float*)d_out;

    float* att_sum = (float*)d_ws;            // N*4 floats = 800 KB
    float* wt_ih   = att_sum + (size_t)NN * HH;
    float* wt_hh   = wt_ih + (size_t)G3 * DD;

    hipMemsetAsync(out, 0, (size_t)NN * 512 * sizeof(float), stream);
    hipMemsetAsync(att_sum, 0, (size_t)NN * HH * sizeof(float), stream);

    prep_kernel<<<(G3 * DD + 255) / 256, 256, 0, stream>>>(w_ih, w_hh, wt_ih, wt_hh);

    gru_att_kernel<<<PP / TM, NT, 0, stream>>>(x, path_list, wt_ih, wt_hh,
                                               b_ih, b_hh, a, att_sum, out);

    normalize_kernel<<<(NN * 512 + 255) / 256, 256, 0, stream>>>(out, att_sum);
}

// Round 2
// 877.975 us; speedup vs baseline: 5.2089x; 5.2089x over previous
//
#include <hip/hip_runtime.h>
#include <hip/hip_bf16.h>
#include <math.h>

// Problem constants
#define NN 50000
#define PP 200000
#define LL 6
#define DD 128      // IN_DIM == OUT_DIM
#define HH 4        // heads

// Tiling
#define TM 64       // paths per workgroup
#define NT 512      // threads per workgroup (8 waves)
#define XPAD 152    // bf16 row stride for xs/hsb: 304B -> 16B aligned, 2-way banks (free)
#define HPAD 132    // fp32 row stride for hs: 2-way banks

typedef __attribute__((ext_vector_type(8))) short short8;   // 8 bf16 = 4 VGPR (MFMA A/B frag)
typedef __attribute__((ext_vector_type(4))) float f32x4;    // MFMA C/D frag

__device__ __forceinline__ unsigned short f2bf(float v) {
    __hip_bfloat16 h = __float2bfloat16(v);
    return *(unsigned short*)&h;
}
__device__ __forceinline__ float sigmoid_fast(float x) {
    return 1.f / (1.f + __expf(-x));
}
__device__ __forceinline__ float tanh_fast(float x) {
    // overflow-safe: tanh(x) = sign(x) * (1 - 2/(e^{2|x|}+1))
    float ax = fabsf(x);
    float e  = __expf(2.f * ax);
    float t  = 1.f - 2.f / (e + 1.f);
    return copysignf(t, x);
}

// ---------------------------------------------------------------------------
// Prep: cast x and weights to bf16. w_ih/w_hh are [384][128] row-major, which
// is already exactly the MFMA B-fragment order (gate row, k-contiguous).
// ---------------------------------------------------------------------------
__global__ void prep_x_kernel(const float* __restrict__ x,
                              unsigned short* __restrict__ xb) {
    int i = blockIdx.x * 256 + threadIdx.x;   // over N*128 = 6.4M
    if (i < NN * DD) xb[i] = f2bf(x[i]);
}
__global__ void prep_w_kernel(const float* __restrict__ w_ih,
                              const float* __restrict__ w_hh,
                              unsigned short* __restrict__ wib,
                              unsigned short* __restrict__ whb) {
    int i = blockIdx.x * 256 + threadIdx.x;   // over 384*128
    if (i < 3 * DD * DD) { wib[i] = f2bf(w_ih[i]); whb[i] = f2bf(w_hh[i]); }
}

// ---------------------------------------------------------------------------
// Fused MFMA GRU + attention.
// Wave w owns d-slice [16w, 16w+16). For its d's it computes gate columns
// {d, 128+d, 256+d} so the whole GRU cell update is wave-local.
// B fragments (both weight matrices, this wave's 48 gate rows) are loaded
// ONCE into 96 persistent VGPRs — zero weight re-staging across the 6 steps.
// ---------------------------------------------------------------------------
__global__ __launch_bounds__(NT, 2)
void gru_att_kernel(const unsigned short* __restrict__ xb,   // [N][128] bf16
                    const int*   __restrict__ path_list,
                    const unsigned short* __restrict__ wib,  // [384][128] bf16
                    const unsigned short* __restrict__ whb,  // [384][128] bf16
                    const float* __restrict__ b_ih,
                    const float* __restrict__ b_hh,
                    const float* __restrict__ a,             // [128][4]
                    float* __restrict__ att_sum,             // [N][4]
                    float* __restrict__ out)                 // [N][512]
{
    // smem layout (73984 B total):
    //   hs   fp32 [TM][HPAD]                 @ 0       (33792 B)
    //   hsb  bf16 [TM][XPAD]                 @ 33792   (19456 B)
    //   xs   bf16 [TM][XPAD]                 @ 53248   (19456 B)  (overlaid by red_s after t-loop)
    //   rows int  [TM]                       @ 72704   (256 B)
    //   attun fp32 [TM][HH]                  @ 72960   (1024 B)
    __shared__ __align__(16) unsigned char smem[73984];
    float*          hs    = (float*)smem;
    unsigned short* hsb   = (unsigned short*)(smem + 33792);
    unsigned short* xs    = (unsigned short*)(smem + 53248);
    int*            rows_s= (int*)(smem + 72704);
    float*          attun = (float*)(smem + 72960);
    float*          red_s = (float*)xs;      // [TM][8][HH] = 8KB, xs dead after t-loop

    const int tid  = threadIdx.x;
    const int lane = tid & 63;
    const int wave = tid >> 6;        // 0..7
    const int lcol = lane & 15;       // MFMA n-index (and A m-index)
    const int quad = lane >> 4;       // 0..3
    const int d    = wave * 16 + lcol;   // this lane's gate/hidden column
    const int p0   = blockIdx.x * TM;

    // ---- persistent B fragments: B[k][n] = W[n][k], lane n = lcol, k = ks*32+quad*8+j
    short8 Bxr[4], Bxz[4], Bxn[4], Bhr[4], Bhz[4], Bhn[4];
    {
        const int ko = quad * 8;
        #pragma unroll
        for (int ks = 0; ks < 4; ++ks) {
            int kk = ks * 32 + ko;
            Bxr[ks] = *(const short8*)(wib + (size_t)(d       ) * DD + kk);
            Bxz[ks] = *(const short8*)(wib + (size_t)(d + 128 ) * DD + kk);
            Bxn[ks] = *(const short8*)(wib + (size_t)(d + 256 ) * DD + kk);
            Bhr[ks] = *(const short8*)(whb + (size_t)(d       ) * DD + kk);
            Bhz[ks] = *(const short8*)(whb + (size_t)(d + 128 ) * DD + kk);
            Bhn[ks] = *(const short8*)(whb + (size_t)(d + 256 ) * DD + kk);
        }
    }
    const float brz = b_ih[d]       + b_hh[d];
    const float bzz = b_ih[d + 128] + b_hh[d + 128];
    const float bin = b_ih[d + 256];
    const float bhn = b_hh[d + 256];

    // h0 = 0
    for (int i = tid; i < TM * XPAD; i += NT) hsb[i] = 0;
    for (int i = tid; i < TM * HPAD; i += NT) hs[i] = 0.f;

    f32x4 accR[4], accZ[4], accN[4], accH[4];

    for (int t = 0; t < LL; ++t) {
        __syncthreads();   // prior epilogue writes visible; prior xs reads done
        // ---- gather x_t (bf16 rows, 32B per thread) ----
        {
            int pi = tid >> 3, tt = tid & 7;
            int node = path_list[(p0 + pi) * LL + t];
            if (t == LL - 1 && tt == 0) rows_s[pi] = node;
            const uint4* src = (const uint4*)(xb + (size_t)node * DD + tt * 16);
            uint4* dst = (uint4*)(xs + pi * XPAD + tt * 16);
            dst[0] = src[0];
            dst[1] = src[1];
        }
        __syncthreads();

        #pragma unroll
        for (int rt = 0; rt < 4; ++rt) {
            accR[rt] = (f32x4){brz, brz, brz, brz};
            accZ[rt] = (f32x4){bzz, bzz, bzz, bzz};
            accN[rt] = (f32x4){bin, bin, bin, bin};
            accH[rt] = (f32x4){bhn, bhn, bhn, bhn};
        }

        // ---- x phase: gi contributions (r, z, i_n) ----
        #pragma unroll
        for (int ks = 0; ks < 4; ++ks) {
            int ka = ks * 32 + quad * 8;
            #pragma unroll
            for (int rt = 0; rt < 4; ++rt) {
                short8 av = *(const short8*)(xs + (rt * 16 + lcol) * XPAD + ka);
                accR[rt] = __builtin_amdgcn_mfma_f32_16x16x32_bf16(av, Bxr[ks], accR[rt], 0, 0, 0);
                accZ[rt] = __builtin_amdgcn_mfma_f32_16x16x32_bf16(av, Bxz[ks], accZ[rt], 0, 0, 0);
                accN[rt] = __builtin_amdgcn_mfma_f32_16x16x32_bf16(av, Bxn[ks], accN[rt], 0, 0, 0);
            }
        }
        // ---- h phase: gh contributions (r, z combined; h_n separate) ----
        #pragma unroll
        for (int ks = 0; ks < 4; ++ks) {
            int ka = ks * 32 + quad * 8;
            #pragma unroll
            for (int rt = 0; rt < 4; ++rt) {
                short8 av = *(const short8*)(hsb + (rt * 16 + lcol) * XPAD + ka);
                accR[rt] = __builtin_amdgcn_mfma_f32_16x16x32_bf16(av, Bhr[ks], accR[rt], 0, 0, 0);
                accZ[rt] = __builtin_amdgcn_mfma_f32_16x16x32_bf16(av, Bhz[ks], accZ[rt], 0, 0, 0);
                accH[rt] = __builtin_amdgcn_mfma_f32_16x16x32_bf16(av, Bhn[ks], accH[rt], 0, 0, 0);
            }
        }

        __syncthreads();   // all waves done reading hsb/xs before h update

        // ---- GRU cell epilogue (wave-local: lane owns (p, d) pairs) ----
        #pragma unroll
        for (int rt = 0; rt < 4; ++rt) {
            #pragma unroll
            for (int r = 0; r < 4; ++r) {
                int p = rt * 16 + quad * 4 + r;   // C/D layout: row = quad*4 + reg
                float rg = sigmoid_fast(accR[rt][r]);
                float zg = sigmoid_fast(accZ[rt][r]);
                float ng = tanh_fast(accN[rt][r] + rg * accH[rt][r]);
                float hold = hs[p * HPAD + d];
                float hnew = (1.f - zg) * ng + zg * hold;
                hs[p * HPAD + d]  = hnew;
                hsb[p * XPAD + d] = f2bf(hnew);
            }
        }
    }

    __syncthreads();   // final h visible; xs dead -> red_s overlay is safe

    // ---- attention logits ----
    {
        int pi = tid >> 3, tt = tid & 7;
        float s0 = 0.f, s1 = 0.f, s2 = 0.f, s3 = 0.f;
        #pragma unroll
        for (int j = 0; j < 16; ++j) {
            int dd2 = tt * 16 + j;
            float hv = hs[pi * HPAD + dd2];
            float4 av = *(const float4*)(a + dd2 * 4);
            s0 += hv * av.x; s1 += hv * av.y; s2 += hv * av.z; s3 += hv * av.w;
        }
        float* rp = red_s + (pi * 8 + tt) * 4;
        rp[0] = s0; rp[1] = s1; rp[2] = s2; rp[3] = s3;
    }
    __syncthreads();
    if (tid < TM) {
        int pi = tid;
        int row = rows_s[pi];
        #pragma unroll
        for (int h = 0; h < HH; ++h) {
            float s = 0.f;
            #pragma unroll
            for (int tt = 0; tt < 8; ++tt) s += red_s[(pi * 8 + tt) * 4 + h];
            float lv = (s > 0.f) ? s : 0.2f * s;
            float e  = __expf(lv);
            attun[pi * HH + h] = e;
            atomicAdd(&att_sum[row * HH + h], e);
        }
    }
    __syncthreads();

    // ---- unnormalized numerator: each iter writes one path's 512-col row ----
    for (int e = tid; e < TM * 512; e += NT) {
        int pi = e >> 9;
        int c  = e & 511;
        int h  = c >> 7;
        int dd2 = c & 127;
        float v = attun[pi * HH + h] * hs[pi * HPAD + dd2];
        atomicAdd(&out[(size_t)rows_s[pi] * 512 + c], v);
    }
}

// ---------------------------------------------------------------------------
// Normalize: out[n][h*128+d] /= att_sum[n][h]  (guard empty nodes: 0/0 -> 0)
// ---------------------------------------------------------------------------
__global__ void normalize_kernel(float* __restrict__ out,
                                 const float* __restrict__ att_sum) {
    int i = blockIdx.x * 256 + threadIdx.x;   // over N*512 = 25.6M
    if (i < NN * 512) {
        int n = i >> 9;
        int h = (i >> 7) & 3;
        float s = att_sum[n * HH + h];
        float v = out[i];
        out[i] = (s > 0.f) ? v / s : 0.f;
    }
}

extern "C" void kernel_launch(void* const* d_in, const int* in_sizes, int n_in,
                              void* d_out, int out_size, void* d_ws, size_t ws_size,
                              hipStream_t stream) {
    const float* x         = (const float*)d_in[0];
    const int*   path_list = (const int*)  d_in[1];
    const float* w_ih      = (const float*)d_in[2];
    const float* w_hh      = (const float*)d_in[3];
    const float* b_ih      = (const float*)d_in[4];
    const float* b_hh      = (const float*)d_in[5];
    const float* a         = (const float*)d_in[6];
    float* out = (float*)d_out;

    // workspace layout (16B-aligned slices): att_sum | xb | wib | whb  (~13.8MB)
    float*          att_sum = (float*)d_ws;                       // 800000 B
    unsigned short* xb      = (unsigned short*)((char*)d_ws + 800000);
    unsigned short* wib     = xb + (size_t)NN * DD;               // +12.8MB
    unsigned short* whb     = wib + 3 * DD * DD;

    hipMemsetAsync(out, 0, (size_t)NN * 512 * sizeof(float), stream);
    hipMemsetAsync(att_sum, 0, (size_t)NN * HH * sizeof(float), stream);

    prep_x_kernel<<<(NN * DD + 255) / 256, 256, 0, stream>>>(x, xb);
    prep_w_kernel<<<(3 * DD * DD + 255) / 256, 256, 0, stream>>>(w_ih, w_hh, wib, whb);

    gru_att_kernel<<<PP / TM, NT, 0, stream>>>(xb, path_list, wib, whb,
                                               b_ih, b_hh, a, att_sum, out);

    normalize_kernel<<<(NN * 512 + 255) / 256, 256, 0, stream>>>(out, att_sum);
}